// Round 1
// baseline (408.317 us; speedup 1.0000x reference)
//
#include <hip/hip_runtime.h>
#include <stdint.h>

// Problem constants
#define T_   2048
#define NH   16
#define HD   64
#define NBH  64     // B*H
#define CDIM 1024
#define MROWS 8192  // B*T

typedef __attribute__((ext_vector_type(8))) short short8;
typedef __attribute__((ext_vector_type(4))) float f32x4;

#define LOG2E 1.44269504088896340736f

static __device__ __forceinline__ uint16_t f2bf(float f) {
  uint32_t u = __float_as_uint(f);
  return (uint16_t)((u + 0x7FFFu + ((u >> 16) & 1u)) >> 16);
}

static __device__ __forceinline__ void async16(const void* g, void* l) {
  __builtin_amdgcn_global_load_lds(
      (const __attribute__((address_space(1))) uint32_t*)g,
      (__attribute__((address_space(3))) uint32_t*)l, 16, 0, 0);
}

// ---------------- fp32 -> bf16 convert ----------------
__global__ __launch_bounds__(256) void cvt_f32_bf16(const float* __restrict__ in,
                                                    uint16_t* __restrict__ out, int n) {
  int i = (blockIdx.x * 256 + threadIdx.x) * 4;
  int stride = gridDim.x * 256 * 4;
  for (; i < n; i += stride) {
    float4 v = *(const float4*)(in + i);
    ushort4 o;
    o.x = f2bf(v.x); o.y = f2bf(v.y); o.z = f2bf(v.z); o.w = f2bf(v.w);
    *(ushort4*)(out + i) = o;
  }
}

// ---------------- GEMM: C[M,N] = A[M,K] * Bt[N,K]^T ----------------
// 128x128 tile, BK=32, 4 waves (2x2 of 64x64), 16x16x32 bf16 MFMA.
// MODE 0: Cout fp32 = acc + bias[col]   (N = row stride)
// MODE 1: QKV scatter epilogue (N total = 3072; col>>10 selects Q/K/V)
template <int MODE>
__global__ __launch_bounds__(256) void gemm_bt(
    const uint16_t* __restrict__ A, const uint16_t* __restrict__ Bt,
    float* __restrict__ Cout, const float* __restrict__ bias,
    uint16_t* __restrict__ Qo, uint16_t* __restrict__ Ko, uint16_t* __restrict__ Vo,
    const int* __restrict__ perm, int N) {
  __shared__ uint16_t lA[128 * 32];
  __shared__ uint16_t lB[128 * 32];

  const int t = threadIdx.x;
  const int lane = t & 63, wv = t >> 6;
  const int gq = lane >> 4, lc = lane & 15;
  const int mbase = blockIdx.x * 128;
  const int nbase = blockIdx.y * 128;
  const int wr = (wv >> 1) * 64, wc = (wv & 1) * 64;

  f32x4 acc[4][4];
#pragma unroll
  for (int i = 0; i < 4; ++i)
#pragma unroll
    for (int j = 0; j < 4; ++j) acc[i][j] = (f32x4){0.f, 0.f, 0.f, 0.f};

  const int srow = t >> 2;            // 0..63 (per issue)
  const int scb  = (t & 3) * 16;      // byte-in-row 0/16/32/48

  for (int kt = 0; kt < 32; ++kt) {
    const char* baseA = (const char*)A + ((size_t)mbase * CDIM + kt * 32) * 2;
    const char* baseB = (const char*)Bt + ((size_t)nbase * CDIM + kt * 32) * 2;
#pragma unroll
    for (int j = 0; j < 2; ++j) {
      int row = j * 64 + srow;
      async16(baseA + (size_t)row * (CDIM * 2) + scb, (char*)lA + j * 4096 + wv * 1024);
    }
#pragma unroll
    for (int j = 0; j < 2; ++j) {
      int row = j * 64 + srow;
      async16(baseB + (size_t)row * (CDIM * 2) + scb, (char*)lB + j * 4096 + wv * 1024);
    }
    asm volatile("s_waitcnt vmcnt(0)" ::: "memory");
    __syncthreads();

    short8 af[4], bfr[4];
#pragma unroll
    for (int mi = 0; mi < 4; ++mi)
      af[mi] = *(const short8*)&lA[(wr + mi * 16 + lc) * 32 + 8 * gq];
#pragma unroll
    for (int ni = 0; ni < 4; ++ni)
      bfr[ni] = *(const short8*)&lB[(wc + ni * 16 + lc) * 32 + 8 * gq];
#pragma unroll
    for (int mi = 0; mi < 4; ++mi)
#pragma unroll
      for (int ni = 0; ni < 4; ++ni)
        acc[mi][ni] = __builtin_amdgcn_mfma_f32_16x16x32_bf16(af[mi], bfr[ni], acc[mi][ni], 0, 0, 0);
    __syncthreads();
  }

  if (MODE == 0) {
#pragma unroll
    for (int mi = 0; mi < 4; ++mi) {
      int row = mbase + wr + mi * 16 + 4 * gq;
#pragma unroll
      for (int ni = 0; ni < 4; ++ni) {
        int col = nbase + wc + ni * 16 + lc;
        float bv = bias[col];
#pragma unroll
        for (int r = 0; r < 4; ++r)
          Cout[(size_t)(row + r) * N + col] = acc[mi][ni][r] + bv;
      }
    }
  } else {
#pragma unroll
    for (int mi = 0; mi < 4; ++mi) {
#pragma unroll
      for (int r = 0; r < 4; ++r) {
        int m = mbase + wr + mi * 16 + 4 * gq + r;
        int b = m >> 11, s = m & 2047;
        int p = perm[s];
#pragma unroll
        for (int ni = 0; ni < 4; ++ni) {
          int col = nbase + wc + ni * 16 + lc;
          int typ = col >> 10, cc = col & 1023;
          int h = cc >> 6, d = cc & 63;
          int bh = b * 16 + h;
          float v = acc[mi][ni][r];
          if (typ == 0)
            Qo[((size_t)bh * T_ + s) * HD + d] = f2bf(v * 0.125f);  // exact pow2 scale
          else if (typ == 1)
            Ko[((size_t)bh * T_ + p) * HD + d] = f2bf(v);
          else
            Vo[((size_t)bh * T_ + p) * HD + d] = f2bf(v);
        }
      }
    }
  }
}

// ---------------- V transpose: [bh][p][d] -> [bh][d][p] ----------------
__global__ __launch_bounds__(256) void transpose_v(const uint16_t* __restrict__ Vp,
                                                   uint16_t* __restrict__ Vt) {
  __shared__ uint16_t tile[64][72];
  const int pb = blockIdx.x * 64;
  const int bh = blockIdx.y;
  const int t = threadIdx.x;
  const uint16_t* src = Vp + (size_t)bh * T_ * HD + (size_t)pb * HD;
#pragma unroll
  for (int it = 0; it < 2; ++it) {
    int lin = it * 256 + t;
    int row = lin >> 3, col = (lin & 7) * 8;
    short8 v = *(const short8*)(src + row * HD + col);
    *(short8*)&tile[row][col] = v;
  }
  __syncthreads();
  uint16_t* dst = Vt + (size_t)bh * HD * T_;
#pragma unroll
  for (int it = 0; it < 2; ++it) {
    int lin = it * 256 + t;
    int d = lin >> 3, ps = (lin & 7) * 8;
    short8 v;
#pragma unroll
    for (int j = 0; j < 8; ++j) v[j] = (short)tile[ps + j][d];
    *(short8*)(dst + (size_t)d * T_ + pb + ps) = v;
  }
}

// ---------------- causal flash attention on permuted K/V ----------------
// grid: (T/128, NBH); 4 waves x 32 q-rows. KV tiles of 32 keys.
__global__ __launch_bounds__(256) void attn_kernel(
    const uint16_t* __restrict__ Q, const uint16_t* __restrict__ Kp,
    const uint16_t* __restrict__ Vt, uint16_t* __restrict__ Y) {
  __shared__ uint16_t plds[4][2][16][32];
  const int bh = blockIdx.y;
  const int b = bh >> 4, h = bh & 15;
  const int qb = blockIdx.x * 128;
  const int t = threadIdx.x;
  const int lane = t & 63, wv = t >> 6;
  const int gq = lane >> 4, lc = lane & 15;
  const int qw = qb + wv * 32;

  const uint16_t* Qb = Q + ((size_t)bh * T_ + qw) * HD;
  const uint16_t* Kb = Kp + (size_t)bh * T_ * HD;
  const uint16_t* Vb = Vt + (size_t)bh * HD * T_;

  short8 qf[2][2];
#pragma unroll
  for (int fi = 0; fi < 2; ++fi)
#pragma unroll
    for (int kh = 0; kh < 2; ++kh)
      qf[fi][kh] = *(const short8*)(Qb + (size_t)(fi * 16 + lc) * HD + kh * 32 + 8 * gq);

  f32x4 o[2][4];
  float mrow[2][4], lrow[2][4];
#pragma unroll
  for (int fi = 0; fi < 2; ++fi) {
#pragma unroll
    for (int dc = 0; dc < 4; ++dc) o[fi][dc] = (f32x4){0.f, 0.f, 0.f, 0.f};
#pragma unroll
    for (int r = 0; r < 4; ++r) { mrow[fi][r] = -__builtin_inff(); lrow[fi][r] = 0.f; }
  }

  const int nkt = (qw >> 5) + 1;  // per-wave causal tile count
  for (int kt = 0; kt < nkt; ++kt) {
    const int p0 = kt * 32;
    short8 kf[2][2];
#pragma unroll
    for (int ct = 0; ct < 2; ++ct)
#pragma unroll
      for (int kh = 0; kh < 2; ++kh)
        kf[ct][kh] = *(const short8*)(Kb + (size_t)(p0 + ct * 16 + lc) * HD + kh * 32 + 8 * gq);

    f32x4 s[2][2];
    const f32x4 z = (f32x4){0.f, 0.f, 0.f, 0.f};
#pragma unroll
    for (int fi = 0; fi < 2; ++fi)
#pragma unroll
      for (int ct = 0; ct < 2; ++ct) {
        f32x4 t0 = __builtin_amdgcn_mfma_f32_16x16x32_bf16(qf[fi][0], kf[ct][0], z, 0, 0, 0);
        s[fi][ct] = __builtin_amdgcn_mfma_f32_16x16x32_bf16(qf[fi][1], kf[ct][1], t0, 0, 0, 0);
      }

    // causal mask: key p allowed iff p <= q
#pragma unroll
    for (int fi = 0; fi < 2; ++fi)
#pragma unroll
      for (int ct = 0; ct < 2; ++ct) {
        int p = p0 + ct * 16 + lc;
        int qrow = qw + fi * 16 + 4 * gq;
#pragma unroll
        for (int r = 0; r < 4; ++r)
          if (p > qrow + r) s[fi][ct][r] = -__builtin_inff();
      }

    // online softmax per fi (rows live in 16-lane groups)
#pragma unroll
    for (int fi = 0; fi < 2; ++fi) {
      float tm[4];
#pragma unroll
      for (int r = 0; r < 4; ++r) tm[r] = fmaxf(s[fi][0][r], s[fi][1][r]);
#pragma unroll
      for (int msk = 1; msk < 16; msk <<= 1)
#pragma unroll
        for (int r = 0; r < 4; ++r) tm[r] = fmaxf(tm[r], __shfl_xor(tm[r], msk));
      float mnew[4], alpha[4];
#pragma unroll
      for (int r = 0; r < 4; ++r) {
        mnew[r] = fmaxf(mrow[fi][r], tm[r]);
        alpha[r] = __builtin_amdgcn_exp2f((mrow[fi][r] - mnew[r]) * LOG2E);
        mrow[fi][r] = mnew[r];
      }
#pragma unroll
      for (int ct = 0; ct < 2; ++ct)
#pragma unroll
        for (int r = 0; r < 4; ++r)
          s[fi][ct][r] = __builtin_amdgcn_exp2f((s[fi][ct][r] - mnew[r]) * LOG2E);
      float rs[4];
#pragma unroll
      for (int r = 0; r < 4; ++r) rs[r] = s[fi][0][r] + s[fi][1][r];
#pragma unroll
      for (int msk = 1; msk < 16; msk <<= 1)
#pragma unroll
        for (int r = 0; r < 4; ++r) rs[r] += __shfl_xor(rs[r], msk);
#pragma unroll
      for (int r = 0; r < 4; ++r) lrow[fi][r] = lrow[fi][r] * alpha[r] + rs[r];
#pragma unroll
      for (int dc = 0; dc < 4; ++dc)
#pragma unroll
        for (int r = 0; r < 4; ++r) o[fi][dc][r] *= alpha[r];
      // pack P to LDS (wave-private)
#pragma unroll
      for (int ct = 0; ct < 2; ++ct)
#pragma unroll
        for (int r = 0; r < 4; ++r)
          plds[wv][fi][4 * gq + r][ct * 16 + lc] = f2bf(s[fi][ct][r]);
    }

    short8 pa[2];
#pragma unroll
    for (int fi = 0; fi < 2; ++fi)
      pa[fi] = *(const short8*)&plds[wv][fi][lc][8 * gq];
    short8 vf[4];
#pragma unroll
    for (int dc = 0; dc < 4; ++dc)
      vf[dc] = *(const short8*)(Vb + (size_t)(dc * 16 + lc) * T_ + p0 + 8 * gq);
#pragma unroll
    for (int fi = 0; fi < 2; ++fi)
#pragma unroll
      for (int dc = 0; dc < 4; ++dc)
        o[fi][dc] = __builtin_amdgcn_mfma_f32_16x16x32_bf16(pa[fi], vf[dc], o[fi][dc], 0, 0, 0);
  }

  // epilogue: O /= l, write Y[b*T+s][h*64+d] bf16
#pragma unroll
  for (int fi = 0; fi < 2; ++fi) {
    float inv[4];
#pragma unroll
    for (int r = 0; r < 4; ++r) inv[r] = 1.0f / lrow[fi][r];
#pragma unroll
    for (int dc = 0; dc < 4; ++dc)
#pragma unroll
      for (int r = 0; r < 4; ++r) {
        int srow = qw + fi * 16 + 4 * gq + r;
        Y[((size_t)b * T_ + srow) * CDIM + h * HD + dc * 16 + lc] = f2bf(o[fi][dc][r] * inv[r]);
      }
  }
}

// ---------------- launch ----------------
extern "C" void kernel_launch(void* const* d_in, const int* in_sizes, int n_in,
                              void* d_out, int out_size, void* d_ws, size_t ws_size,
                              hipStream_t stream) {
  const float* x = (const float*)d_in[0];
  const float* wqkv = (const float*)d_in[1];
  const float* wproj = (const float*)d_in[2];
  const float* bproj = (const float*)d_in[3];
  const int* perm = (const int*)d_in[4];
  float* out = (float*)d_out;

  char* ws = (char*)d_ws;
  // workspace layout (bytes); total = 92,274,688 (~88 MB)
  uint16_t* xb     = (uint16_t*)(ws + 0);          // 16 MB (reused as Y later)
  uint16_t* wqkvb  = (uint16_t*)(ws + 16777216);   // 6 MB
  uint16_t* wprojb = (uint16_t*)(ws + 23068672);   // 2 MB
  uint16_t* Qb     = (uint16_t*)(ws + 25165824);   // 16 MB
  uint16_t* Kb     = (uint16_t*)(ws + 41943040);   // 16 MB
  uint16_t* Vpb    = (uint16_t*)(ws + 58720256);   // 16 MB
  uint16_t* Vtb    = (uint16_t*)(ws + 75497472);   // 16 MB
  uint16_t* Yb     = xb;                           // reuse (x no longer needed)

  cvt_f32_bf16<<<2048, 256, 0, stream>>>(x, xb, MROWS * CDIM);
  cvt_f32_bf16<<<1024, 256, 0, stream>>>(wqkv, wqkvb, 3 * CDIM * CDIM);
  cvt_f32_bf16<<<512, 256, 0, stream>>>(wproj, wprojb, CDIM * CDIM);

  gemm_bt<1><<<dim3(64, 24), 256, 0, stream>>>(xb, wqkvb, nullptr, nullptr,
                                               Qb, Kb, Vpb, perm, 3072);
  transpose_v<<<dim3(32, 64), 256, 0, stream>>>(Vpb, Vtb);
  attn_kernel<<<dim3(16, 64), 256, 0, stream>>>(Qb, Kb, Vtb, Yb);
  gemm_bt<0><<<dim3(64, 8), 256, 0, stream>>>(Yb, wprojb, out, bproj,
                                              nullptr, nullptr, nullptr, nullptr, CDIM);
}

// Round 4
// 251.468 us; speedup vs baseline: 1.6237x; 1.6237x over previous
//
#include <hip/hip_runtime.h>
#include <stdint.h>

// Problem constants
#define T_   2048
#define NH   16
#define HD   64
#define NBH  64     // B*H
#define CDIM 1024
#define MROWS 8192  // B*T

typedef __attribute__((ext_vector_type(8))) short short8;
typedef __attribute__((ext_vector_type(4))) float f32x4;
typedef __attribute__((ext_vector_type(16))) float f32x16;
typedef __attribute__((ext_vector_type(2))) unsigned int uint32x2;

#define LOG2E 1.44269504088896340736f

static __device__ __forceinline__ uint16_t f2bf(float f) {
  uint32_t u = __float_as_uint(f);
  return (uint16_t)((u + 0x7FFFu + ((u >> 16) & 1u)) >> 16);
}

static __device__ __forceinline__ void async16(const void* g, void* l) {
  __builtin_amdgcn_global_load_lds(
      (const __attribute__((address_space(1))) uint32_t*)g,
      (__attribute__((address_space(3))) uint32_t*)l, 16, 0, 0);
}

// permlane32_swap via the documented gfx950 builtin (value semantics, no
// inline-asm register hazards). Returns {vdst_new, vsrc_new}:
//   r[0] = {lane<32: a[lane],     lane>=32: b[lane-32]}
//   r[1] = {lane<32: a[lane+32],  lane>=32: b[lane]}
static __device__ __forceinline__ uint32x2 plswap(uint32_t a, uint32_t b) {
  return __builtin_amdgcn_permlane32_swap(a, b, false, false);
}
static __device__ __forceinline__ float halves_max(float x) {
  uint32x2 r = plswap(__float_as_uint(x), __float_as_uint(x));
  return fmaxf(__uint_as_float(r[0]), __uint_as_float(r[1]));
}
static __device__ __forceinline__ float halves_sum(float x) {
  uint32x2 r = plswap(__float_as_uint(x), __float_as_uint(x));
  return __uint_as_float(r[0]) + __uint_as_float(r[1]);
}
static __device__ __forceinline__ uint32_t pkbf(float lo, float hi) {
  uint32_t r;
  asm("v_cvt_pk_bf16_f32 %0, %1, %2" : "=v"(r) : "v"(lo), "v"(hi));
  return r;
}

// ---------------- fp32 -> bf16 convert ----------------
__global__ __launch_bounds__(256) void cvt_f32_bf16(const float* __restrict__ in,
                                                    uint16_t* __restrict__ out, int n) {
  int i = (blockIdx.x * 256 + threadIdx.x) * 4;
  int stride = gridDim.x * 256 * 4;
  for (; i < n; i += stride) {
    float4 v = *(const float4*)(in + i);
    ushort4 o;
    o.x = f2bf(v.x); o.y = f2bf(v.y); o.z = f2bf(v.z); o.w = f2bf(v.w);
    *(ushort4*)(out + i) = o;
  }
}

// ---------------- GEMM: C[M,N] = A[M,K] * Bt[N,K]^T ----------------
// 128x128 tile, BK=32, 4 waves (2x2 of 64x64), 16x16x32 bf16 MFMA.
// MODE 0: Cout fp32 = acc + bias[col]   (N = row stride)
// MODE 1: QKV scatter epilogue (N total = 3072; col>>10 selects Q/K/V)
template <int MODE>
__global__ __launch_bounds__(256) void gemm_bt(
    const uint16_t* __restrict__ A, const uint16_t* __restrict__ Bt,
    float* __restrict__ Cout, const float* __restrict__ bias,
    uint16_t* __restrict__ Qo, uint16_t* __restrict__ Ko, uint16_t* __restrict__ Vo,
    const int* __restrict__ perm, int N) {
  __shared__ uint16_t lA[128 * 32];
  __shared__ uint16_t lB[128 * 32];

  const int t = threadIdx.x;
  const int lane = t & 63, wv = t >> 6;
  const int gq = lane >> 4, lc = lane & 15;
  const int mbase = blockIdx.x * 128;
  const int nbase = blockIdx.y * 128;
  const int wr = (wv >> 1) * 64, wc = (wv & 1) * 64;

  f32x4 acc[4][4];
#pragma unroll
  for (int i = 0; i < 4; ++i)
#pragma unroll
    for (int j = 0; j < 4; ++j) acc[i][j] = (f32x4){0.f, 0.f, 0.f, 0.f};

  const int srow = t >> 2;            // 0..63 (per issue)
  const int scb  = (t & 3) * 16;      // byte-in-row 0/16/32/48

  for (int kt = 0; kt < 32; ++kt) {
    const char* baseA = (const char*)A + ((size_t)mbase * CDIM + kt * 32) * 2;
    const char* baseB = (const char*)Bt + ((size_t)nbase * CDIM + kt * 32) * 2;
#pragma unroll
    for (int j = 0; j < 2; ++j) {
      int row = j * 64 + srow;
      async16(baseA + (size_t)row * (CDIM * 2) + scb, (char*)lA + j * 4096 + wv * 1024);
    }
#pragma unroll
    for (int j = 0; j < 2; ++j) {
      int row = j * 64 + srow;
      async16(baseB + (size_t)row * (CDIM * 2) + scb, (char*)lB + j * 4096 + wv * 1024);
    }
    asm volatile("s_waitcnt vmcnt(0)" ::: "memory");
    __syncthreads();

    short8 af[4], bfr[4];
#pragma unroll
    for (int mi = 0; mi < 4; ++mi)
      af[mi] = *(const short8*)&lA[(wr + mi * 16 + lc) * 32 + 8 * gq];
#pragma unroll
    for (int ni = 0; ni < 4; ++ni)
      bfr[ni] = *(const short8*)&lB[(wc + ni * 16 + lc) * 32 + 8 * gq];
#pragma unroll
    for (int mi = 0; mi < 4; ++mi)
#pragma unroll
      for (int ni = 0; ni < 4; ++ni)
        acc[mi][ni] = __builtin_amdgcn_mfma_f32_16x16x32_bf16(af[mi], bfr[ni], acc[mi][ni], 0, 0, 0);
    __syncthreads();
  }

  if (MODE == 0) {
#pragma unroll
    for (int mi = 0; mi < 4; ++mi) {
      int row = mbase + wr + mi * 16 + 4 * gq;
#pragma unroll
      for (int ni = 0; ni < 4; ++ni) {
        int col = nbase + wc + ni * 16 + lc;
        float bv = bias[col];
#pragma unroll
        for (int r = 0; r < 4; ++r)
          Cout[(size_t)(row + r) * N + col] = acc[mi][ni][r] + bv;
      }
    }
  } else {
#pragma unroll
    for (int mi = 0; mi < 4; ++mi) {
#pragma unroll
      for (int r = 0; r < 4; ++r) {
        int m = mbase + wr + mi * 16 + 4 * gq + r;
        int b = m >> 11, s = m & 2047;
        int p = perm[s];
#pragma unroll
        for (int ni = 0; ni < 4; ++ni) {
          int col = nbase + wc + ni * 16 + lc;
          int typ = col >> 10, cc = col & 1023;
          int h = cc >> 6, d = cc & 63;
          int bh = b * 16 + h;
          float v = acc[mi][ni][r];
          if (typ == 0)
            Qo[((size_t)bh * T_ + s) * HD + d] = f2bf(v * (0.125f * LOG2E));  // fold 1/sqrt(D), log2(e)
          else if (typ == 1)
            Ko[((size_t)bh * T_ + p) * HD + d] = f2bf(v);
          else
            Vo[((size_t)bh * T_ + p) * HD + d] = f2bf(v);
        }
      }
    }
  }
}

// ---------------- V transpose: [bh][p][d] -> [bh][d][p] ----------------
__global__ __launch_bounds__(256) void transpose_v(const uint16_t* __restrict__ Vp,
                                                   uint16_t* __restrict__ Vt) {
  __shared__ uint16_t tile[64][72];
  const int pb = blockIdx.x * 64;
  const int bh = blockIdx.y;
  const int t = threadIdx.x;
  const uint16_t* src = Vp + (size_t)bh * T_ * HD + (size_t)pb * HD;
#pragma unroll
  for (int it = 0; it < 2; ++it) {
    int lin = it * 256 + t;
    int row = lin >> 3, col = (lin & 7) * 8;
    short8 v = *(const short8*)(src + row * HD + col);
    *(short8*)&tile[row][col] = v;
  }
  __syncthreads();
  uint16_t* dst = Vt + (size_t)bh * HD * T_;
#pragma unroll
  for (int it = 0; it < 2; ++it) {
    int lin = it * 256 + t;
    int d = lin >> 3, ps = (lin & 7) * 8;
    short8 v;
#pragma unroll
    for (int j = 0; j < 8; ++j) v[j] = (short)tile[ps + j][d];
    *(short8*)(dst + (size_t)d * T_ + pb + ps) = v;
  }
}

// ---------------- causal flash attention, swapped-operand 32x32 ----------------
// grid: (NBH, T/128); block = 4 waves, each wave owns 32 q rows.
// St = mfma_32x32x16(K, Q): col(lane&31)=q, row=(r&3)+8*(r>>2)+4*(lane>>5)=key.
// Each lane holds 32 of its q-row's keys; partner lane (lane^32) has the rest.
// P is redistributed into PV B-frags with v_cvt_pk_bf16_f32 + permlane32_swap.
// O accumulated transposed (q in cols) so alpha/l rescales are lane-local.
// Q pre-scaled by (1/8)*log2(e) so softmax runs in exp2 domain.
__global__ __launch_bounds__(256, 2) void attn_kernel(
    const uint16_t* __restrict__ Q, const uint16_t* __restrict__ Kp,
    const uint16_t* __restrict__ Vt, uint16_t* __restrict__ Y) {
  const int bh = blockIdx.x;
  const int b = bh >> 4, h = bh & 15;
  const int qb = (gridDim.y - 1 - blockIdx.y) * 128;  // heavy blocks first
  const int t = threadIdx.x;
  const int lane = t & 63, wv = t >> 6;
  const int l31 = lane & 31, hi = lane >> 5;
  const int qw = qb + wv * 32;
  const int qg = qw + l31;  // this lane's q row (column of St)

  const uint16_t* Qb = Q + ((size_t)bh * T_ + qw) * HD;
  const uint16_t* Kb = Kp + (size_t)bh * T_ * HD;
  const uint16_t* Vb = Vt + (size_t)bh * HD * T_;

  // Q B-frags: qf[kc] = Q[q=l31][d = 16kc + 8hi + j]
  short8 qf[4];
#pragma unroll
  for (int kc = 0; kc < 4; ++kc)
    qf[kc] = *(const short8*)(Qb + (size_t)l31 * HD + 16 * kc + 8 * hi);

  f32x16 ot[2];
#pragma unroll
  for (int dt = 0; dt < 2; ++dt)
#pragma unroll
    for (int r = 0; r < 16; ++r) ot[dt][r] = 0.f;
  float mrun = -__builtin_inff();
  float lrun = 0.f;

  const int nkt = (qw >> 6) + 1;  // 64-key tiles; only the last needs masking
  for (int kt = 0; kt < nkt; ++kt) {
    const int p0 = kt * 64;
    // K A-frags: kf[a][kc] = K[key = p0+32a+l31][d = 16kc+8hi+j]
    short8 kf[2][4];
#pragma unroll
    for (int a = 0; a < 2; ++a)
#pragma unroll
      for (int kc = 0; kc < 4; ++kc)
        kf[a][kc] = *(const short8*)(Kb + (size_t)(p0 + 32 * a + l31) * HD + 16 * kc + 8 * hi);
    // V A-frags: vf[dt][kc] = Vt[d = 32dt+l31][p = p0 + 16kc + 8hi + j]
    short8 vf[2][4];
#pragma unroll
    for (int dt = 0; dt < 2; ++dt)
#pragma unroll
      for (int kc = 0; kc < 4; ++kc)
        vf[dt][kc] = *(const short8*)(Vb + (size_t)(32 * dt + l31) * T_ + p0 + 16 * kc + 8 * hi);

    // QK^T (swapped): st[a][r] = S[key][q=lane&31]
    f32x16 st[2];
#pragma unroll
    for (int a = 0; a < 2; ++a) {
#pragma unroll
      for (int r = 0; r < 16; ++r) st[a][r] = 0.f;
#pragma unroll
      for (int kc = 0; kc < 4; ++kc)
        st[a] = __builtin_amdgcn_mfma_f32_32x32x16_bf16(kf[a][kc], qf[kc], st[a], 0, 0, 0);
    }

    if (kt == nkt - 1) {  // diagonal tile: mask key > q
#pragma unroll
      for (int a = 0; a < 2; ++a) {
        int kbase = p0 + 32 * a + 4 * hi;
#pragma unroll
        for (int r = 0; r < 16; ++r) {
          int key = kbase + (r & 3) + 8 * (r >> 2);
          if (key > qg) st[a][r] = -__builtin_inff();
        }
      }
    }

    // row max: 31 in-lane ops + cross-half combine
    float mloc = st[0][0];
#pragma unroll
    for (int r = 1; r < 16; ++r) mloc = fmaxf(mloc, st[0][r]);
#pragma unroll
    for (int r = 0; r < 16; ++r) mloc = fmaxf(mloc, st[1][r]);
    float mall = halves_max(mloc);
    float mnew = fmaxf(mrun, mall);
    float alpha = __builtin_amdgcn_exp2f(mrun - mnew);
    mrun = mnew;

    // p = exp2(s - m) (S already in log2 domain)
#pragma unroll
    for (int a = 0; a < 2; ++a)
#pragma unroll
      for (int r = 0; r < 16; ++r)
        st[a][r] = __builtin_amdgcn_exp2f(st[a][r] - mnew);

    float sl = 0.f;
#pragma unroll
    for (int a = 0; a < 2; ++a)
#pragma unroll
      for (int r = 0; r < 16; ++r) sl += st[a][r];
    lrun = lrun * alpha + halves_sum(sl);

    // rescale O^T (alpha is lane-local: q = col)
#pragma unroll
    for (int dt = 0; dt < 2; ++dt)
#pragma unroll
      for (int r = 0; r < 16; ++r) ot[dt][r] *= alpha;

    // build P B-frags: chunk kc uses p-regs 8kc..8kc+7 (keys 16kc+..)
#pragma unroll
    for (int kc = 0; kc < 4; ++kc) {
#define PV_(i) ((8 * kc + (i)) < 16 ? st[0][(8 * kc + (i)) & 15] : st[1][(8 * kc + (i)) & 15])
      uint32_t u0 = pkbf(PV_(0), PV_(1));
      uint32_t u1 = pkbf(PV_(2), PV_(3));
      uint32_t u2 = pkbf(PV_(4), PV_(5));
      uint32_t u3 = pkbf(PV_(6), PV_(7));
#undef PV_
      uint32x2 s02 = plswap(u0, u2);  // [0]->words j{0,1}, [1]->words j{4,5}
      uint32x2 s13 = plswap(u1, u3);  // [0]->j{2,3}, [1]->j{6,7}
      union { uint32_t w[4]; short8 s; } pb;
      pb.w[0] = s02[0]; pb.w[1] = s13[0]; pb.w[2] = s02[1]; pb.w[3] = s13[1];
#pragma unroll
      for (int dt = 0; dt < 2; ++dt)
        ot[dt] = __builtin_amdgcn_mfma_f32_32x32x16_bf16(vf[dt][kc], pb.s, ot[dt], 0, 0, 0);
    }
  }

  // epilogue: O^T[d][q]/l -> Y[b*T+q][h*64+d], 8B packed stores
  float inv = 1.0f / lrun;
  uint16_t* Yrow = Y + ((size_t)b * T_ + qg) * CDIM + h * HD;
#pragma unroll
  for (int dt = 0; dt < 2; ++dt)
#pragma unroll
    for (int g = 0; g < 4; ++g) {
      int d0 = 32 * dt + 8 * g + 4 * hi;
      ushort4 o4;
      o4.x = f2bf(ot[dt][4 * g + 0] * inv);
      o4.y = f2bf(ot[dt][4 * g + 1] * inv);
      o4.z = f2bf(ot[dt][4 * g + 2] * inv);
      o4.w = f2bf(ot[dt][4 * g + 3] * inv);
      *(ushort4*)(Yrow + d0) = o4;
    }
}

// ---------------- launch ----------------
extern "C" void kernel_launch(void* const* d_in, const int* in_sizes, int n_in,
                              void* d_out, int out_size, void* d_ws, size_t ws_size,
                              hipStream_t stream) {
  const float* x = (const float*)d_in[0];
  const float* wqkv = (const float*)d_in[1];
  const float* wproj = (const float*)d_in[2];
  const float* bproj = (const float*)d_in[3];
  const int* perm = (const int*)d_in[4];
  float* out = (float*)d_out;

  char* ws = (char*)d_ws;
  // workspace layout (bytes); total = 92,274,688 (~88 MB)
  uint16_t* xb     = (uint16_t*)(ws + 0);          // 16 MB (reused as Y later)
  uint16_t* wqkvb  = (uint16_t*)(ws + 16777216);   // 6 MB
  uint16_t* wprojb = (uint16_t*)(ws + 23068672);   // 2 MB
  uint16_t* Qb     = (uint16_t*)(ws + 25165824);   // 16 MB
  uint16_t* Kb     = (uint16_t*)(ws + 41943040);   // 16 MB
  uint16_t* Vpb    = (uint16_t*)(ws + 58720256);   // 16 MB
  uint16_t* Vtb    = (uint16_t*)(ws + 75497472);   // 16 MB
  uint16_t* Yb     = xb;                           // reuse (x no longer needed)

  cvt_f32_bf16<<<2048, 256, 0, stream>>>(x, xb, MROWS * CDIM);
  cvt_f32_bf16<<<1024, 256, 0, stream>>>(wqkv, wqkvb, 3 * CDIM * CDIM);
  cvt_f32_bf16<<<512, 256, 0, stream>>>(wproj, wprojb, CDIM * CDIM);

  gemm_bt<1><<<dim3(64, 24), 256, 0, stream>>>(xb, wqkvb, nullptr, nullptr,
                                               Qb, Kb, Vpb, perm, 3072);
  transpose_v<<<dim3(32, 64), 256, 0, stream>>>(Vpb, Vtb);
  attn_kernel<<<dim3(64, 16), 256, 0, stream>>>(Qb, Kb, Vtb, Yb);
  gemm_bt<0><<<dim3(64, 8), 256, 0, stream>>>(Yb, wprojb, out, bproj,
                                              nullptr, nullptr, nullptr, nullptr, CDIM);
}

// Round 5
// 246.216 us; speedup vs baseline: 1.6584x; 1.0213x over previous
//
#include <hip/hip_runtime.h>
#include <stdint.h>

// Problem constants
#define T_   2048
#define NH   16
#define HD   64
#define NBH  64     // B*H
#define CDIM 1024
#define MROWS 8192  // B*T

typedef __attribute__((ext_vector_type(8))) short short8;
typedef __attribute__((ext_vector_type(4))) float f32x4;
typedef __attribute__((ext_vector_type(16))) float f32x16;
typedef __attribute__((ext_vector_type(2))) unsigned int uint32x2;

#define LOG2E 1.44269504088896340736f

static __device__ __forceinline__ uint16_t f2bf(float f) {
  uint32_t u = __float_as_uint(f);
  return (uint16_t)((u + 0x7FFFu + ((u >> 16) & 1u)) >> 16);
}

static __device__ __forceinline__ void async16(const void* g, void* l) {
  __builtin_amdgcn_global_load_lds(
      (const __attribute__((address_space(1))) uint32_t*)g,
      (__attribute__((address_space(3))) uint32_t*)l, 16, 0, 0);
}

// permlane32_swap builtin: returns {vdst_new, vsrc_new}:
//   r[0] = {lane<32: a[lane],     lane>=32: b[lane-32]}
//   r[1] = {lane<32: a[lane+32],  lane>=32: b[lane]}
static __device__ __forceinline__ uint32x2 plswap(uint32_t a, uint32_t b) {
  return __builtin_amdgcn_permlane32_swap(a, b, false, false);
}
static __device__ __forceinline__ float halves_max(float x) {
  uint32x2 r = plswap(__float_as_uint(x), __float_as_uint(x));
  return fmaxf(__uint_as_float(r[0]), __uint_as_float(r[1]));
}
static __device__ __forceinline__ float halves_sum(float x) {
  uint32x2 r = plswap(__float_as_uint(x), __float_as_uint(x));
  return __uint_as_float(r[0]) + __uint_as_float(r[1]);
}
static __device__ __forceinline__ uint32_t pkbf(float lo, float hi) {
  uint32_t r;
  asm("v_cvt_pk_bf16_f32 %0, %1, %2" : "=v"(r) : "v"(lo), "v"(hi));
  return r;
}
// tree reductions over two 16-reg score tiles (depth ~5 vs 31 serial)
static __device__ __forceinline__ float tmax32(const f32x16& a, const f32x16& b) {
  float t[16];
#pragma unroll
  for (int r = 0; r < 16; ++r) t[r] = fmaxf(a[r], b[r]);
#pragma unroll
  for (int s = 8; s >= 1; s >>= 1)
#pragma unroll
    for (int r = 0; r < s; ++r) t[r] = fmaxf(t[r], t[r + s]);
  return t[0];
}
static __device__ __forceinline__ float tsum32(const f32x16& a, const f32x16& b) {
  float t[16];
#pragma unroll
  for (int r = 0; r < 16; ++r) t[r] = a[r] + b[r];
#pragma unroll
  for (int s = 8; s >= 1; s >>= 1)
#pragma unroll
    for (int r = 0; r < s; ++r) t[r] += t[r + s];
  return t[0];
}

// ---------------- fp32 -> bf16 convert ----------------
__global__ __launch_bounds__(256) void cvt_f32_bf16(const float* __restrict__ in,
                                                    uint16_t* __restrict__ out, int n) {
  int i = (blockIdx.x * 256 + threadIdx.x) * 4;
  int stride = gridDim.x * 256 * 4;
  for (; i < n; i += stride) {
    float4 v = *(const float4*)(in + i);
    ushort4 o;
    o.x = f2bf(v.x); o.y = f2bf(v.y); o.z = f2bf(v.z); o.w = f2bf(v.w);
    *(ushort4*)(out + i) = o;
  }
}

// ---------------- GEMM: C[M,N] = A[M,K] * Bt[N,K]^T ----------------
// 128x128 tile, BK=32, 4 waves (2x2 of 64x64), 16x16x32 bf16 MFMA.
// MODE 0: Cout fp32 = acc + bias[col]   (N = row stride)
// MODE 1: QKV scatter epilogue (N total = 3072; col>>10 selects Q/K/V)
template <int MODE>
__global__ __launch_bounds__(256) void gemm_bt(
    const uint16_t* __restrict__ A, const uint16_t* __restrict__ Bt,
    float* __restrict__ Cout, const float* __restrict__ bias,
    uint16_t* __restrict__ Qo, uint16_t* __restrict__ Ko, uint16_t* __restrict__ Vo,
    const int* __restrict__ perm, int N) {
  __shared__ uint16_t lA[128 * 32];
  __shared__ uint16_t lB[128 * 32];

  const int t = threadIdx.x;
  const int lane = t & 63, wv = t >> 6;
  const int gq = lane >> 4, lc = lane & 15;
  const int mbase = blockIdx.x * 128;
  const int nbase = blockIdx.y * 128;
  const int wr = (wv >> 1) * 64, wc = (wv & 1) * 64;

  f32x4 acc[4][4];
#pragma unroll
  for (int i = 0; i < 4; ++i)
#pragma unroll
    for (int j = 0; j < 4; ++j) acc[i][j] = (f32x4){0.f, 0.f, 0.f, 0.f};

  const int srow = t >> 2;            // 0..63 (per issue)
  const int scb  = (t & 3) * 16;      // byte-in-row 0/16/32/48

  for (int kt = 0; kt < 32; ++kt) {
    const char* baseA = (const char*)A + ((size_t)mbase * CDIM + kt * 32) * 2;
    const char* baseB = (const char*)Bt + ((size_t)nbase * CDIM + kt * 32) * 2;
#pragma unroll
    for (int j = 0; j < 2; ++j) {
      int row = j * 64 + srow;
      async16(baseA + (size_t)row * (CDIM * 2) + scb, (char*)lA + j * 4096 + wv * 1024);
    }
#pragma unroll
    for (int j = 0; j < 2; ++j) {
      int row = j * 64 + srow;
      async16(baseB + (size_t)row * (CDIM * 2) + scb, (char*)lB + j * 4096 + wv * 1024);
    }
    asm volatile("s_waitcnt vmcnt(0)" ::: "memory");
    __syncthreads();

    short8 af[4], bfr[4];
#pragma unroll
    for (int mi = 0; mi < 4; ++mi)
      af[mi] = *(const short8*)&lA[(wr + mi * 16 + lc) * 32 + 8 * gq];
#pragma unroll
    for (int ni = 0; ni < 4; ++ni)
      bfr[ni] = *(const short8*)&lB[(wc + ni * 16 + lc) * 32 + 8 * gq];
#pragma unroll
    for (int mi = 0; mi < 4; ++mi)
#pragma unroll
      for (int ni = 0; ni < 4; ++ni)
        acc[mi][ni] = __builtin_amdgcn_mfma_f32_16x16x32_bf16(af[mi], bfr[ni], acc[mi][ni], 0, 0, 0);
    __syncthreads();
  }

  if (MODE == 0) {
#pragma unroll
    for (int mi = 0; mi < 4; ++mi) {
      int row = mbase + wr + mi * 16 + 4 * gq;
#pragma unroll
      for (int ni = 0; ni < 4; ++ni) {
        int col = nbase + wc + ni * 16 + lc;
        float bv = bias[col];
#pragma unroll
        for (int r = 0; r < 4; ++r)
          Cout[(size_t)(row + r) * N + col] = acc[mi][ni][r] + bv;
      }
    }
  } else {
#pragma unroll
    for (int mi = 0; mi < 4; ++mi) {
#pragma unroll
      for (int r = 0; r < 4; ++r) {
        int m = mbase + wr + mi * 16 + 4 * gq + r;
        int b = m >> 11, s = m & 2047;
        int p = perm[s];
#pragma unroll
        for (int ni = 0; ni < 4; ++ni) {
          int col = nbase + wc + ni * 16 + lc;
          int typ = col >> 10, cc = col & 1023;
          int h = cc >> 6, d = cc & 63;
          int bh = b * 16 + h;
          float v = acc[mi][ni][r];
          if (typ == 0)
            Qo[((size_t)bh * T_ + s) * HD + d] = f2bf(v * (0.125f * LOG2E));  // fold 1/sqrt(D), log2(e)
          else if (typ == 1)
            Ko[((size_t)bh * T_ + p) * HD + d] = f2bf(v);
          else
            Vo[((size_t)bh * T_ + p) * HD + d] = f2bf(v);
        }
      }
    }
  }
}

// ---------------- V transpose: [bh][p][d] -> [bh][d][p] ----------------
__global__ __launch_bounds__(256) void transpose_v(const uint16_t* __restrict__ Vp,
                                                   uint16_t* __restrict__ Vt) {
  __shared__ uint16_t tile[64][72];
  const int pb = blockIdx.x * 64;
  const int bh = blockIdx.y;
  const int t = threadIdx.x;
  const uint16_t* src = Vp + (size_t)bh * T_ * HD + (size_t)pb * HD;
#pragma unroll
  for (int it = 0; it < 2; ++it) {
    int lin = it * 256 + t;
    int row = lin >> 3, col = (lin & 7) * 8;
    short8 v = *(const short8*)(src + row * HD + col);
    *(short8*)&tile[row][col] = v;
  }
  __syncthreads();
  uint16_t* dst = Vt + (size_t)bh * HD * T_;
#pragma unroll
  for (int it = 0; it < 2; ++it) {
    int lin = it * 256 + t;
    int d = lin >> 3, ps = (lin & 7) * 8;
    short8 v;
#pragma unroll
    for (int j = 0; j < 8; ++j) v[j] = (short)tile[ps + j][d];
    *(short8*)(dst + (size_t)d * T_ + pb + ps) = v;
  }
}

// ---------------- causal flash attention, swapped-operand 32x32 ----------------
// 1 wave per block (64 threads): finer scheduling granularity for the
// imbalanced causal workload + low reg pressure for occupancy.
// grid: (NBH, T/32) with bh fastest -> all q-tiles of one bh on one XCD
// (8 bh/XCD x (K+V=512KB) = 4MB = L2). Heavy q-tiles launch first.
// St = mfma_32x32x16(K, Q): col(lane&31)=q, row=(r&3)+8*(r>>2)+4*(lane>>5)=key.
// Softmax: tree max/sum + defer-max (THR=8) to skip the O-rescale pass.
// P redistributed into PV B-frags with v_cvt_pk_bf16_f32 + permlane32_swap.
// O accumulated transposed (q in cols) so rescales are lane-local.
// Q pre-scaled by (1/8)*log2(e) so softmax runs in exp2 domain.
__global__ __launch_bounds__(64, 3) void attn_kernel(
    const uint16_t* __restrict__ Q, const uint16_t* __restrict__ Kp,
    const uint16_t* __restrict__ Vt, uint16_t* __restrict__ Y) {
  const int bh = blockIdx.x;
  const int b = bh >> 4, h = bh & 15;
  const int qw = (gridDim.y - 1 - blockIdx.y) * 32;  // heavy blocks first
  const int lane = threadIdx.x & 63;
  const int l31 = lane & 31, hi = lane >> 5;
  const int qg = qw + l31;  // this lane's q row (column of St)

  const uint16_t* Qb = Q + ((size_t)bh * T_ + qw) * HD;
  const uint16_t* Kb = Kp + (size_t)bh * T_ * HD;
  const uint16_t* Vb = Vt + (size_t)bh * HD * T_;

  // Q B-frags: qf[kc] = Q[q=l31][d = 16kc + 8hi + j]
  short8 qf[4];
#pragma unroll
  for (int kc = 0; kc < 4; ++kc)
    qf[kc] = *(const short8*)(Qb + (size_t)l31 * HD + 16 * kc + 8 * hi);

  f32x16 ot[2];
#pragma unroll
  for (int dt = 0; dt < 2; ++dt)
#pragma unroll
    for (int r = 0; r < 16; ++r) ot[dt][r] = 0.f;
  float mrun = -__builtin_inff();
  float lrun = 0.f;

  const int nkt = (qw >> 6) + 1;  // 64-key tiles; only the last needs masking
  for (int kt = 0; kt < nkt; ++kt) {
    const int p0 = kt * 64;

    // QK^T (swapped): st[a][r] = S[key][q=lane&31]; K staged per-a to cap regs
    f32x16 st[2];
#pragma unroll
    for (int a = 0; a < 2; ++a) {
      short8 kf[4];
#pragma unroll
      for (int kc = 0; kc < 4; ++kc)
        kf[kc] = *(const short8*)(Kb + (size_t)(p0 + 32 * a + l31) * HD + 16 * kc + 8 * hi);
#pragma unroll
      for (int r = 0; r < 16; ++r) st[a][r] = 0.f;
      __builtin_amdgcn_s_setprio(1);
#pragma unroll
      for (int kc = 0; kc < 4; ++kc)
        st[a] = __builtin_amdgcn_mfma_f32_32x32x16_bf16(kf[kc], qf[kc], st[a], 0, 0, 0);
      __builtin_amdgcn_s_setprio(0);
    }

    if (kt == nkt - 1) {  // diagonal tile: mask key > q
#pragma unroll
      for (int a = 0; a < 2; ++a) {
        int kbase = p0 + 32 * a + 4 * hi;
#pragma unroll
        for (int r = 0; r < 16; ++r) {
          int key = kbase + (r & 3) + 8 * (r >> 2);
          if (key > qg) st[a][r] = -__builtin_inff();
        }
      }
    }

    // defer-max online softmax: rescale only when max grows by > THR
    float mall = halves_max(tmax32(st[0], st[1]));
    if (__any(mall > mrun + 8.0f)) {
      float mnew = fmaxf(mrun, mall);
      float alpha = __builtin_amdgcn_exp2f(mrun - mnew);
      mrun = mnew;
      lrun *= alpha;
#pragma unroll
      for (int dt = 0; dt < 2; ++dt)
#pragma unroll
        for (int r = 0; r < 16; ++r) ot[dt][r] *= alpha;
    }

    // p = exp2(s - m); bounded by 2^8 under defer
#pragma unroll
    for (int a = 0; a < 2; ++a)
#pragma unroll
      for (int r = 0; r < 16; ++r)
        st[a][r] = __builtin_amdgcn_exp2f(st[a][r] - mrun);

    lrun += halves_sum(tsum32(st[0], st[1]));

    // build P B-frags: chunk kc uses p-regs 8kc..8kc+7 (keys 16kc+..)
    short8 pb[4];
#pragma unroll
    for (int kc = 0; kc < 4; ++kc) {
#define PV_(i) ((8 * kc + (i)) < 16 ? st[0][(8 * kc + (i)) & 15] : st[1][(8 * kc + (i)) & 15])
      uint32_t u0 = pkbf(PV_(0), PV_(1));
      uint32_t u1 = pkbf(PV_(2), PV_(3));
      uint32_t u2 = pkbf(PV_(4), PV_(5));
      uint32_t u3 = pkbf(PV_(6), PV_(7));
#undef PV_
      uint32x2 s02 = plswap(u0, u2);  // [0]->words j{0,1}, [1]->words j{4,5}
      uint32x2 s13 = plswap(u1, u3);  // [0]->j{2,3}, [1]->j{6,7}
      union { uint32_t w[4]; short8 s; } pbu;
      pbu.w[0] = s02[0]; pbu.w[1] = s13[0]; pbu.w[2] = s02[1]; pbu.w[3] = s13[1];
      pb[kc] = pbu.s;
    }

    // PV: V staged per-dt to cap regs
#pragma unroll
    for (int dt = 0; dt < 2; ++dt) {
      short8 vf[4];
#pragma unroll
      for (int kc = 0; kc < 4; ++kc)
        vf[kc] = *(const short8*)(Vb + (size_t)(32 * dt + l31) * T_ + p0 + 16 * kc + 8 * hi);
      __builtin_amdgcn_s_setprio(1);
#pragma unroll
      for (int kc = 0; kc < 4; ++kc)
        ot[dt] = __builtin_amdgcn_mfma_f32_32x32x16_bf16(vf[kc], pb[kc], ot[dt], 0, 0, 0);
      __builtin_amdgcn_s_setprio(0);
    }
  }

  // epilogue: O^T[d][q]/l -> Y[b*T+q][h*64+d], 8B packed stores
  float inv = 1.0f / lrun;
  uint16_t* Yrow = Y + ((size_t)b * T_ + qg) * CDIM + h * HD;
#pragma unroll
  for (int dt = 0; dt < 2; ++dt)
#pragma unroll
    for (int g = 0; g < 4; ++g) {
      int d0 = 32 * dt + 8 * g + 4 * hi;
      ushort4 o4;
      o4.x = f2bf(ot[dt][4 * g + 0] * inv);
      o4.y = f2bf(ot[dt][4 * g + 1] * inv);
      o4.z = f2bf(ot[dt][4 * g + 2] * inv);
      o4.w = f2bf(ot[dt][4 * g + 3] * inv);
      *(ushort4*)(Yrow + d0) = o4;
    }
}

// ---------------- launch ----------------
extern "C" void kernel_launch(void* const* d_in, const int* in_sizes, int n_in,
                              void* d_out, int out_size, void* d_ws, size_t ws_size,
                              hipStream_t stream) {
  const float* x = (const float*)d_in[0];
  const float* wqkv = (const float*)d_in[1];
  const float* wproj = (const float*)d_in[2];
  const float* bproj = (const float*)d_in[3];
  const int* perm = (const int*)d_in[4];
  float* out = (float*)d_out;

  char* ws = (char*)d_ws;
  // workspace layout (bytes); total = 92,274,688 (~88 MB)
  uint16_t* xb     = (uint16_t*)(ws + 0);          // 16 MB (reused as Y later)
  uint16_t* wqkvb  = (uint16_t*)(ws + 16777216);   // 6 MB
  uint16_t* wprojb = (uint16_t*)(ws + 23068672);   // 2 MB
  uint16_t* Qb     = (uint16_t*)(ws + 25165824);   // 16 MB
  uint16_t* Kb     = (uint16_t*)(ws + 41943040);   // 16 MB
  uint16_t* Vpb    = (uint16_t*)(ws + 58720256);   // 16 MB
  uint16_t* Vtb    = (uint16_t*)(ws + 75497472);   // 16 MB
  uint16_t* Yb     = xb;                           // reuse (x no longer needed)

  cvt_f32_bf16<<<2048, 256, 0, stream>>>(x, xb, MROWS * CDIM);
  cvt_f32_bf16<<<1024, 256, 0, stream>>>(wqkv, wqkvb, 3 * CDIM * CDIM);
  cvt_f32_bf16<<<512, 256, 0, stream>>>(wproj, wprojb, CDIM * CDIM);

  gemm_bt<1><<<dim3(64, 24), 256, 0, stream>>>(xb, wqkvb, nullptr, nullptr,
                                               Qb, Kb, Vpb, perm, 3072);
  transpose_v<<<dim3(32, 64), 256, 0, stream>>>(Vpb, Vtb);
  attn_kernel<<<dim3(64, 64), 64, 0, stream>>>(Qb, Kb, Vtb, Yb);
  gemm_bt<0><<<dim3(64, 8), 256, 0, stream>>>(Yb, wprojb, out, bproj,
                                              nullptr, nullptr, nullptr, nullptr, CDIM);
}

// Round 6
// 177.406 us; speedup vs baseline: 2.3016x; 1.3879x over previous
//
#include <hip/hip_runtime.h>
#include <stdint.h>

// Problem constants
#define T_   2048
#define NH   16
#define HD   64
#define NBH  64     // B*H
#define CDIM 1024
#define MROWS 8192  // B*T

typedef __attribute__((ext_vector_type(8))) short short8;
typedef __attribute__((ext_vector_type(4))) float f32x4;
typedef __attribute__((ext_vector_type(16))) float f32x16;
typedef __attribute__((ext_vector_type(2))) unsigned int uint32x2;

#define LOG2E 1.44269504088896340736f

static __device__ __forceinline__ uint16_t f2bf(float f) {
  uint32_t u = __float_as_uint(f);
  return (uint16_t)((u + 0x7FFFu + ((u >> 16) & 1u)) >> 16);
}

static __device__ __forceinline__ void async16(const void* g, void* l) {
  __builtin_amdgcn_global_load_lds(
      (const __attribute__((address_space(1))) uint32_t*)g,
      (__attribute__((address_space(3))) uint32_t*)l, 16, 0, 0);
}

// permlane32_swap builtin: returns {vdst_new, vsrc_new}:
//   r[0] = {lane<32: a[lane],     lane>=32: b[lane-32]}
//   r[1] = {lane<32: a[lane+32],  lane>=32: b[lane]}
static __device__ __forceinline__ uint32x2 plswap(uint32_t a, uint32_t b) {
  return __builtin_amdgcn_permlane32_swap(a, b, false, false);
}
static __device__ __forceinline__ float halves_max(float x) {
  uint32x2 r = plswap(__float_as_uint(x), __float_as_uint(x));
  return fmaxf(__uint_as_float(r[0]), __uint_as_float(r[1]));
}
static __device__ __forceinline__ float halves_sum(float x) {
  uint32x2 r = plswap(__float_as_uint(x), __float_as_uint(x));
  return __uint_as_float(r[0]) + __uint_as_float(r[1]);
}
static __device__ __forceinline__ uint32_t pkbf(float lo, float hi) {
  uint32_t r;
  asm("v_cvt_pk_bf16_f32 %0, %1, %2" : "=v"(r) : "v"(lo), "v"(hi));
  return r;
}
// tree reductions over two 16-reg score tiles (depth ~5 vs 31 serial)
static __device__ __forceinline__ float tmax32(const f32x16& a, const f32x16& b) {
  float t[16];
#pragma unroll
  for (int r = 0; r < 16; ++r) t[r] = fmaxf(a[r], b[r]);
#pragma unroll
  for (int s = 8; s >= 1; s >>= 1)
#pragma unroll
    for (int r = 0; r < s; ++r) t[r] = fmaxf(t[r], t[r + s]);
  return t[0];
}
static __device__ __forceinline__ float tsum32(const f32x16& a, const f32x16& b) {
  float t[16];
#pragma unroll
  for (int r = 0; r < 16; ++r) t[r] = a[r] + b[r];
#pragma unroll
  for (int s = 8; s >= 1; s >>= 1)
#pragma unroll
    for (int r = 0; r < s; ++r) t[r] += t[r + s];
  return t[0];
}

// ---------------- fp32 -> bf16 convert ----------------
__global__ __launch_bounds__(256) void cvt_f32_bf16(const float* __restrict__ in,
                                                    uint16_t* __restrict__ out, int n) {
  int i = (blockIdx.x * 256 + threadIdx.x) * 4;
  int stride = gridDim.x * 256 * 4;
  for (; i < n; i += stride) {
    float4 v = *(const float4*)(in + i);
    ushort4 o;
    o.x = f2bf(v.x); o.y = f2bf(v.y); o.z = f2bf(v.z); o.w = f2bf(v.w);
    *(ushort4*)(out + i) = o;
  }
}

// ---------------- GEMM: C[M,N] = A[M,K] * Bt[N,K]^T ----------------
// 128x128 tile, BK=32, 4 waves (2x2 of 64x64), 16x16x32 bf16 MFMA.
// MODE 0: Cout fp32 = acc + bias[col]   (N = row stride)
// MODE 1: QKV scatter epilogue (N total = 3072; col>>10 selects Q/K/V)
template <int MODE>
__global__ __launch_bounds__(256) void gemm_bt(
    const uint16_t* __restrict__ A, const uint16_t* __restrict__ Bt,
    float* __restrict__ Cout, const float* __restrict__ bias,
    uint16_t* __restrict__ Qo, uint16_t* __restrict__ Ko, uint16_t* __restrict__ Vo,
    const int* __restrict__ perm, int N) {
  __shared__ uint16_t lA[128 * 32];
  __shared__ uint16_t lB[128 * 32];

  const int t = threadIdx.x;
  const int lane = t & 63, wv = t >> 6;
  const int gq = lane >> 4, lc = lane & 15;
  const int mbase = blockIdx.x * 128;
  const int nbase = blockIdx.y * 128;
  const int wr = (wv >> 1) * 64, wc = (wv & 1) * 64;

  f32x4 acc[4][4];
#pragma unroll
  for (int i = 0; i < 4; ++i)
#pragma unroll
    for (int j = 0; j < 4; ++j) acc[i][j] = (f32x4){0.f, 0.f, 0.f, 0.f};

  const int srow = t >> 2;            // 0..63 (per issue)
  const int scb  = (t & 3) * 16;      // byte-in-row 0/16/32/48

  for (int kt = 0; kt < 32; ++kt) {
    const char* baseA = (const char*)A + ((size_t)mbase * CDIM + kt * 32) * 2;
    const char* baseB = (const char*)Bt + ((size_t)nbase * CDIM + kt * 32) * 2;
#pragma unroll
    for (int j = 0; j < 2; ++j) {
      int row = j * 64 + srow;
      async16(baseA + (size_t)row * (CDIM * 2) + scb, (char*)lA + j * 4096 + wv * 1024);
    }
#pragma unroll
    for (int j = 0; j < 2; ++j) {
      int row = j * 64 + srow;
      async16(baseB + (size_t)row * (CDIM * 2) + scb, (char*)lB + j * 4096 + wv * 1024);
    }
    asm volatile("s_waitcnt vmcnt(0)" ::: "memory");
    __syncthreads();

    short8 af[4], bfr[4];
#pragma unroll
    for (int mi = 0; mi < 4; ++mi)
      af[mi] = *(const short8*)&lA[(wr + mi * 16 + lc) * 32 + 8 * gq];
#pragma unroll
    for (int ni = 0; ni < 4; ++ni)
      bfr[ni] = *(const short8*)&lB[(wc + ni * 16 + lc) * 32 + 8 * gq];
#pragma unroll
    for (int mi = 0; mi < 4; ++mi)
#pragma unroll
      for (int ni = 0; ni < 4; ++ni)
        acc[mi][ni] = __builtin_amdgcn_mfma_f32_16x16x32_bf16(af[mi], bfr[ni], acc[mi][ni], 0, 0, 0);
    __syncthreads();
  }

  if (MODE == 0) {
#pragma unroll
    for (int mi = 0; mi < 4; ++mi) {
      int row = mbase + wr + mi * 16 + 4 * gq;
#pragma unroll
      for (int ni = 0; ni < 4; ++ni) {
        int col = nbase + wc + ni * 16 + lc;
        float bv = bias[col];
#pragma unroll
        for (int r = 0; r < 4; ++r)
          Cout[(size_t)(row + r) * N + col] = acc[mi][ni][r] + bv;
      }
    }
  } else {
#pragma unroll
    for (int mi = 0; mi < 4; ++mi) {
#pragma unroll
      for (int r = 0; r < 4; ++r) {
        int m = mbase + wr + mi * 16 + 4 * gq + r;
        int b = m >> 11, s = m & 2047;
        int p = perm[s];
#pragma unroll
        for (int ni = 0; ni < 4; ++ni) {
          int col = nbase + wc + ni * 16 + lc;
          int typ = col >> 10, cc = col & 1023;
          int h = cc >> 6, d = cc & 63;
          int bh = b * 16 + h;
          float v = acc[mi][ni][r];
          if (typ == 0)
            Qo[((size_t)bh * T_ + s) * HD + d] = f2bf(v * (0.125f * LOG2E));  // fold 1/sqrt(D), log2(e)
          else if (typ == 1)
            Ko[((size_t)bh * T_ + p) * HD + d] = f2bf(v);
          else
            Vo[((size_t)bh * T_ + p) * HD + d] = f2bf(v);
        }
      }
    }
  }
}

// ---------------- V transpose: [bh][p][d] -> [bh][d][p] ----------------
__global__ __launch_bounds__(256) void transpose_v(const uint16_t* __restrict__ Vp,
                                                   uint16_t* __restrict__ Vt) {
  __shared__ uint16_t tile[64][72];
  const int pb = blockIdx.x * 64;
  const int bh = blockIdx.y;
  const int t = threadIdx.x;
  const uint16_t* src = Vp + (size_t)bh * T_ * HD + (size_t)pb * HD;
#pragma unroll
  for (int it = 0; it < 2; ++it) {
    int lin = it * 256 + t;
    int row = lin >> 3, col = (lin & 7) * 8;
    short8 v = *(const short8*)(src + row * HD + col);
    *(short8*)&tile[row][col] = v;
  }
  __syncthreads();
  uint16_t* dst = Vt + (size_t)bh * HD * T_;
#pragma unroll
  for (int it = 0; it < 2; ++it) {
    int lin = it * 256 + t;
    int d = lin >> 3, ps = (lin & 7) * 8;
    short8 v;
#pragma unroll
    for (int j = 0; j < 8; ++j) v[j] = (short)tile[ps + j][d];
    *(short8*)(dst + (size_t)d * T_ + pb + ps) = v;
  }
}

// ---------------- causal flash attention, swapped-operand 32x32 ----------------
// R6: LDS-staged K/V tiles. R5 was TA/L1-throughput-bound: per-lane scattered
// fragment loads touched 64 cache lines per instruction (~270k line-lookups
// per CU = whole runtime). Now each 64-key tile of K (8KB, [row][d]) and
// V (8KB, [d][p]) is staged into LDS by all 4 waves via coalesced
// global_load_lds (1KB/instr, 16 instrs/tile = 128 lines), double-buffered
// with counted vmcnt(4). Fragments come from LDS ds_read_b128 with the T2
// XOR swizzle (chunk ^= row&7), applied by pre-swizzling the per-lane GLOBAL
// source address (LDS dest must stay linear) -> conflict-free reads.
// grid: (NBH, T/128) bh-fastest (L2 locality per XCD), heavy q-tiles first.
// Math identical to R5: swapped QK^T (St = mfma(K,Q)), tree reductions,
// defer-max (THR=8), cvt_pk+permlane P redistribution, O^T accumulation.
__global__ __launch_bounds__(256, 4) void attn_kernel(
    const uint16_t* __restrict__ Q, const uint16_t* __restrict__ Kp,
    const uint16_t* __restrict__ Vt, uint16_t* __restrict__ Y) {
  __shared__ __attribute__((aligned(16))) uint16_t lK[2][64 * 64];
  __shared__ __attribute__((aligned(16))) uint16_t lV[2][64 * 64];

  const int bh = blockIdx.x;
  const int b = bh >> 4, h = bh & 15;
  const int qb = (gridDim.y - 1 - blockIdx.y) * 128;  // heavy blocks first
  const int t = threadIdx.x;
  const int lane = t & 63, wv = t >> 6;
  const int l31 = lane & 31, hi = lane >> 5;
  const int qw = qb + 32 * wv;
  const int qg = qw + l31;  // this lane's q row (column of St)

  const uint16_t* Qb = Q + ((size_t)bh * T_ + qw) * HD;
  const uint16_t* Kb = Kp + (size_t)bh * T_ * HD;
  const uint16_t* Vb = Vt + (size_t)bh * HD * T_;

  // staging decomposition: instr i covers tile rows 8i..8i+7 (1KB each);
  // lane -> row 8i+(lane>>3), 16B chunk (lane&7); source chunk XOR-swizzled.
  const int srow8 = lane >> 3;               // 0..7
  const int schunk = (lane & 7) ^ srow8;     // swizzled source chunk (16B units)

  // Q B-frags: qf[kc] = Q[q=l31][d = 16kc + 8hi + j] (one-time, scattered ok)
  short8 qf[4];
#pragma unroll
  for (int kc = 0; kc < 4; ++kc)
    qf[kc] = *(const short8*)(Qb + (size_t)l31 * HD + 16 * kc + 8 * hi);

  f32x16 ot[2];
#pragma unroll
  for (int dt = 0; dt < 2; ++dt)
#pragma unroll
    for (int r = 0; r < 16; ++r) ot[dt][r] = 0.f;
  float mrun = -__builtin_inff();
  float lrun = 0.f;

  const int nkt_blk = (qb >> 6) + 2;  // block-level 64-key tile count
  const int myKt = qw >> 6;           // this wave's last (diagonal) tile

  // prologue: stage tile 0 into buf 0 (4 instrs/wave)
  {
    const int p0 = 0;
#pragma unroll
    for (int j = 0; j < 2; ++j) {
      int i = 2 * wv + j;
      async16(Kb + (size_t)(p0 + 8 * i + srow8) * HD + schunk * 8,
              (char*)&lK[0][0] + i * 1024);
      async16(Vb + (size_t)(8 * i + srow8) * T_ + p0 + schunk * 8,
              (char*)&lV[0][0] + i * 1024);
    }
  }

  const int swz = (l31 & 7);  // read-side XOR (row&7)

  for (int kt = 0; kt < nkt_blk; ++kt) {
    const int cur = kt & 1;
    const int p0 = kt * 64;
    if (kt + 1 < nkt_blk) {
      const int pn = p0 + 64;
#pragma unroll
      for (int j = 0; j < 2; ++j) {
        int i = 2 * wv + j;
        async16(Kb + (size_t)(pn + 8 * i + srow8) * HD + schunk * 8,
                (char*)&lK[cur ^ 1][0] + i * 1024);
        async16(Vb + (size_t)(8 * i + srow8) * T_ + pn + schunk * 8,
                (char*)&lV[cur ^ 1][0] + i * 1024);
      }
      asm volatile("s_waitcnt vmcnt(4)" ::: "memory");  // current tile landed
    } else {
      asm volatile("s_waitcnt vmcnt(0)" ::: "memory");
    }
    __syncthreads();

    if (kt <= myKt) {
      const uint16_t* lk = &lK[cur][0];
      const uint16_t* lv = &lV[cur][0];

      // QK^T (swapped): st[a][r] = S[key][q=lane&31]
      f32x16 st[2];
#pragma unroll
      for (int a = 0; a < 2; ++a) {
        short8 kf[4];
#pragma unroll
        for (int kc = 0; kc < 4; ++kc)
          kf[kc] = *(const short8*)&lk[(32 * a + l31) * 64 + (((2 * kc + hi) ^ swz) * 8)];
#pragma unroll
        for (int r = 0; r < 16; ++r) st[a][r] = 0.f;
        __builtin_amdgcn_s_setprio(1);
#pragma unroll
        for (int kc = 0; kc < 4; ++kc)
          st[a] = __builtin_amdgcn_mfma_f32_32x32x16_bf16(kf[kc], qf[kc], st[a], 0, 0, 0);
        __builtin_amdgcn_s_setprio(0);
      }

      if (kt == myKt) {  // diagonal tile: mask key > q
#pragma unroll
        for (int a = 0; a < 2; ++a) {
          int kbase = p0 + 32 * a + 4 * hi;
#pragma unroll
          for (int r = 0; r < 16; ++r) {
            int key = kbase + (r & 3) + 8 * (r >> 2);
            if (key > qg) st[a][r] = -__builtin_inff();
          }
        }
      }

      // defer-max online softmax: rescale only when max grows by > THR
      float mall = halves_max(tmax32(st[0], st[1]));
      if (__any(mall > mrun + 8.0f)) {
        float mnew = fmaxf(mrun, mall);
        float alpha = __builtin_amdgcn_exp2f(mrun - mnew);
        mrun = mnew;
        lrun *= alpha;
#pragma unroll
        for (int dt = 0; dt < 2; ++dt)
#pragma unroll
          for (int r = 0; r < 16; ++r) ot[dt][r] *= alpha;
      }

      // p = exp2(s - m); bounded by 2^8 under defer
#pragma unroll
      for (int a = 0; a < 2; ++a)
#pragma unroll
        for (int r = 0; r < 16; ++r)
          st[a][r] = __builtin_amdgcn_exp2f(st[a][r] - mrun);

      lrun += halves_sum(tsum32(st[0], st[1]));

      // build P B-frags: chunk kc uses p-regs 8kc..8kc+7
      short8 pb[4];
#pragma unroll
      for (int kc = 0; kc < 4; ++kc) {
#define PV_(i) ((8 * kc + (i)) < 16 ? st[0][(8 * kc + (i)) & 15] : st[1][(8 * kc + (i)) & 15])
        uint32_t u0 = pkbf(PV_(0), PV_(1));
        uint32_t u1 = pkbf(PV_(2), PV_(3));
        uint32_t u2 = pkbf(PV_(4), PV_(5));
        uint32_t u3 = pkbf(PV_(6), PV_(7));
#undef PV_
        uint32x2 s02 = plswap(u0, u2);
        uint32x2 s13 = plswap(u1, u3);
        union { uint32_t w[4]; short8 s; } pbu;
        pbu.w[0] = s02[0]; pbu.w[1] = s13[0]; pbu.w[2] = s02[1]; pbu.w[3] = s13[1];
        pb[kc] = pbu.s;
      }

      // PV: V frags from LDS, staged per-dt
#pragma unroll
      for (int dt = 0; dt < 2; ++dt) {
        short8 vf[4];
#pragma unroll
        for (int kc = 0; kc < 4; ++kc)
          vf[kc] = *(const short8*)&lv[(32 * dt + l31) * 64 + (((2 * kc + hi) ^ swz) * 8)];
        __builtin_amdgcn_s_setprio(1);
#pragma unroll
        for (int kc = 0; kc < 4; ++kc)
          ot[dt] = __builtin_amdgcn_mfma_f32_32x32x16_bf16(vf[kc], pb[kc], ot[dt], 0, 0, 0);
        __builtin_amdgcn_s_setprio(0);
      }
    }
    __syncthreads();
  }

  // epilogue: O^T[d][q]/l -> Y[b*T+q][h*64+d], 8B packed stores
  float inv = 1.0f / lrun;
  uint16_t* Yrow = Y + ((size_t)b * T_ + qg) * CDIM + h * HD;
#pragma unroll
  for (int dt = 0; dt < 2; ++dt)
#pragma unroll
    for (int g = 0; g < 4; ++g) {
      int d0 = 32 * dt + 8 * g + 4 * hi;
      ushort4 o4;
      o4.x = f2bf(ot[dt][4 * g + 0] * inv);
      o4.y = f2bf(ot[dt][4 * g + 1] * inv);
      o4.z = f2bf(ot[dt][4 * g + 2] * inv);
      o4.w = f2bf(ot[dt][4 * g + 3] * inv);
      *(ushort4*)(Yrow + d0) = o4;
    }
}

// ---------------- launch ----------------
extern "C" void kernel_launch(void* const* d_in, const int* in_sizes, int n_in,
                              void* d_out, int out_size, void* d_ws, size_t ws_size,
                              hipStream_t stream) {
  const float* x = (const float*)d_in[0];
  const float* wqkv = (const float*)d_in[1];
  const float* wproj = (const float*)d_in[2];
  const float* bproj = (const float*)d_in[3];
  const int* perm = (const int*)d_in[4];
  float* out = (float*)d_out;

  char* ws = (char*)d_ws;
  // workspace layout (bytes); total = 92,274,688 (~88 MB)
  uint16_t* xb     = (uint16_t*)(ws + 0);          // 16 MB (reused as Y later)
  uint16_t* wqkvb  = (uint16_t*)(ws + 16777216);   // 6 MB
  uint16_t* wprojb = (uint16_t*)(ws + 23068672);   // 2 MB
  uint16_t* Qb     = (uint16_t*)(ws + 25165824);   // 16 MB
  uint16_t* Kb     = (uint16_t*)(ws + 41943040);   // 16 MB
  uint16_t* Vpb    = (uint16_t*)(ws + 58720256);   // 16 MB
  uint16_t* Vtb    = (uint16_t*)(ws + 75497472);   // 16 MB
  uint16_t* Yb     = xb;                           // reuse (x no longer needed)

  cvt_f32_bf16<<<2048, 256, 0, stream>>>(x, xb, MROWS * CDIM);
  cvt_f32_bf16<<<1024, 256, 0, stream>>>(wqkv, wqkvb, 3 * CDIM * CDIM);
  cvt_f32_bf16<<<512, 256, 0, stream>>>(wproj, wprojb, CDIM * CDIM);

  gemm_bt<1><<<dim3(64, 24), 256, 0, stream>>>(xb, wqkvb, nullptr, nullptr,
                                               Qb, Kb, Vpb, perm, 3072);
  transpose_v<<<dim3(32, 64), 256, 0, stream>>>(Vpb, Vtb);
  attn_kernel<<<dim3(64, 16), 256, 0, stream>>>(Qb, Kb, Vtb, Yb);
  gemm_bt<0><<<dim3(64, 8), 256, 0, stream>>>(Yb, wprojb, out, bproj,
                                              nullptr, nullptr, nullptr, nullptr, CDIM);
}